// Round 9
// baseline (440.922 us; speedup 1.0000x reference)
//
#include <hip/hip_runtime.h>
#include <hip/hip_bf16.h>

#define NEG_SLOPE 0.2f

typedef __attribute__((ext_vector_type(8))) short bf16x8;
typedef __attribute__((ext_vector_type(4))) float f32x4;

__device__ __forceinline__ unsigned short f2bf(float v) {
    union { float f; unsigned int u; } x; x.f = v;
    unsigned int r = x.u + 0x7fffu + ((x.u >> 16) & 1u);
    return (unsigned short)(r >> 16);
}
__device__ __forceinline__ float bf2f(unsigned short b) {
    union { unsigned int u; float f; } x; x.u = ((unsigned int)b) << 16;
    return x.f;
}

// ---------------- CSR build ----------------

__global__ void count_edges_k(const int* __restrict__ ei, int E, int n, int* __restrict__ cnt) {
    int e = blockIdx.x * 256 + threadIdx.x;
    int ET = E + n;
    if (e >= ET) return;
    int d = (e < E) ? ei[E + e] : (e - E);
    atomicAdd(&cnt[d], 1);
}

__global__ void scan1_k(const int* __restrict__ cnt, int* __restrict__ row_ptr,
                        int* __restrict__ bsums, int n) {
    __shared__ int sd[256];
    int b = blockIdx.x, t = threadIdx.x;
    int base = b * 1024 + t * 4;
    int v[4];
    int loc = 0;
#pragma unroll
    for (int j = 0; j < 4; ++j) {
        v[j] = (base + j < n) ? cnt[base + j] : 0;
        loc += v[j];
    }
    sd[t] = loc;
    __syncthreads();
    for (int off = 1; off < 256; off <<= 1) {
        int x = (t >= off) ? sd[t - off] : 0;
        __syncthreads();
        sd[t] += x;
        __syncthreads();
    }
    int run = sd[t] - loc;
    if (t == 255) bsums[b] = sd[t];
#pragma unroll
    for (int j = 0; j < 4; ++j) {
        if (base + j < n) row_ptr[base + j] = run;
        run += v[j];
    }
}

__global__ void scan2_k(int* __restrict__ bsums, int nb) {
    if (threadIdx.x == 0 && blockIdx.x == 0) {
        int run = 0;
        for (int i = 0; i < nb; ++i) { int x = bsums[i]; bsums[i] = run; run += x; }
    }
}

__global__ void scan3_k(int* __restrict__ row_ptr, int* __restrict__ pos,
                        const int* __restrict__ bsums, int n, int total) {
    int idx = blockIdx.x * 256 + threadIdx.x;
    if (idx < n) {
        int vv = row_ptr[idx] + bsums[idx >> 10];
        row_ptr[idx] = vv;
        pos[idx] = vv;
    } else if (idx == n) {
        row_ptr[n] = total;
    }
}

__global__ void scatter_edges_k(const int* __restrict__ ei, int E, int n,
                                int* __restrict__ pos, int* __restrict__ srcs) {
    int e = blockIdx.x * 256 + threadIdx.x;
    int ET = E + n;
    if (e >= ET) return;
    int s, d;
    if (e < E) { s = ei[e]; d = ei[E + e]; }
    else       { s = e - E; d = e - E; }
    int idx = atomicAdd(&pos[d], 1);
    srcs[idx] = s;
}

// ---------------- weight pre-convert (all layers, one launch) ----------------

#define R1 (128 * 256)
#define R2 (256 * 256)
#define R3 (256 * 128)

__global__ void convert_w_all_k(const float* __restrict__ W1, const float* __restrict__ W2,
                                const float* __restrict__ W3,
                                unsigned short* __restrict__ b1h, unsigned short* __restrict__ b1l,
                                unsigned short* __restrict__ b2h, unsigned short* __restrict__ b2l,
                                unsigned short* __restrict__ b3h, unsigned short* __restrict__ b3l) {
    int idx = blockIdx.x * 256 + threadIdx.x;
    float v;
    unsigned short* dh;
    unsigned short* dl;
    int o;
    if (idx < R1) {
        int k = idx >> 8, c = idx & 255;
        v = W1[idx]; dh = b1h; dl = b1l; o = c * 128 + k;
    } else if (idx < R1 + R2) {
        int j = idx - R1;
        int k = j >> 8, c = j & 255;
        v = W2[j]; dh = b2h; dl = b2l; o = c * 256 + k;
    } else if (idx < R1 + R2 + R3) {
        int j = idx - (R1 + R2);
        int k = j >> 7, c = j & 127;
        v = (c < 40) ? W3[k * 40 + c] : 0.f;
        dh = b3h; dl = b3l; o = c * 256 + k;
    } else {
        return;
    }
    unsigned short h = f2bf(v);
    dh[o] = h;
    dl[o] = f2bf(v - bf2f(h));
}

// ---------------- layer-1 GEMM: fp32 A split on the fly (3 products) ----------------

#define GPAD 40

__global__ __launch_bounds__(256) void mfma_gemm_k(const float* __restrict__ A,
                                                   const unsigned short* __restrict__ Bh,
                                                   const unsigned short* __restrict__ Bl,
                                                   unsigned short* __restrict__ Cb,
                                                   int M, int K, int Nc) {
    __shared__ unsigned short Ash[128][GPAD];
    __shared__ unsigned short Asl[128][GPAD];
    __shared__ unsigned short Bsh[128][GPAD];
    __shared__ unsigned short Bsl[128][GPAD];

    int bm = blockIdx.y * 128;
    int bn = blockIdx.x * 128;
    int t = threadIdx.x;
    int w = t >> 6, l = t & 63;
    int wm = w >> 1, wn = w & 1;
    int lr = l & 15, lk = (l >> 4) * 8;

    int srow = t >> 1;
    int skh  = (t & 1) * 16;

    f32x4 acc[4][4];
#pragma unroll
    for (int i = 0; i < 4; ++i)
#pragma unroll
        for (int j = 0; j < 4; ++j)
            acc[i][j] = (f32x4){0.f, 0.f, 0.f, 0.f};

    const int arow = bm + srow;
    const bool arow_ok = (arow < M);
    const size_t acol_base = (size_t)arow * K + skh;
    const size_t bcol_base = (size_t)(bn + srow) * K + skh;

    for (int k0 = 0; k0 < K; k0 += 32) {
        float vv[16];
        if (arow_ok) {
            const float4* ap = reinterpret_cast<const float4*>(A + acol_base + k0);
#pragma unroll
            for (int q = 0; q < 4; ++q) {
                float4 v4 = ap[q];
                vv[4 * q + 0] = v4.x; vv[4 * q + 1] = v4.y;
                vv[4 * q + 2] = v4.z; vv[4 * q + 3] = v4.w;
            }
        } else {
#pragma unroll
            for (int q = 0; q < 16; ++q) vv[q] = 0.f;
        }
        unsigned int hw[8], lw[8];
#pragma unroll
        for (int q = 0; q < 8; ++q) {
            unsigned short h0 = f2bf(vv[2 * q]);
            unsigned short h1 = f2bf(vv[2 * q + 1]);
            unsigned short l0 = f2bf(vv[2 * q] - bf2f(h0));
            unsigned short l1 = f2bf(vv[2 * q + 1] - bf2f(h1));
            hw[q] = (unsigned int)h0 | ((unsigned int)h1 << 16);
            lw[q] = (unsigned int)l0 | ((unsigned int)l1 << 16);
        }
        __syncthreads();
        {
            uint4* dh = reinterpret_cast<uint4*>(&Ash[srow][skh]);
            uint4* dl = reinterpret_cast<uint4*>(&Asl[srow][skh]);
            dh[0] = make_uint4(hw[0], hw[1], hw[2], hw[3]);
            dh[1] = make_uint4(hw[4], hw[5], hw[6], hw[7]);
            dl[0] = make_uint4(lw[0], lw[1], lw[2], lw[3]);
            dl[1] = make_uint4(lw[4], lw[5], lw[6], lw[7]);
        }
        {
            const uint4* sh = reinterpret_cast<const uint4*>(Bh + bcol_base + k0);
            const uint4* sl = reinterpret_cast<const uint4*>(Bl + bcol_base + k0);
            uint4* dh = reinterpret_cast<uint4*>(&Bsh[srow][skh]);
            uint4* dl = reinterpret_cast<uint4*>(&Bsl[srow][skh]);
            dh[0] = sh[0]; dh[1] = sh[1];
            dl[0] = sl[0]; dl[1] = sl[1];
        }
        __syncthreads();

        bf16x8 ah[4], al[4], bh[4], bl[4];
#pragma unroll
        for (int i = 0; i < 4; ++i) {
            int r = wm * 64 + i * 16 + lr;
            ah[i] = *reinterpret_cast<const bf16x8*>(&Ash[r][lk]);
            al[i] = *reinterpret_cast<const bf16x8*>(&Asl[r][lk]);
        }
#pragma unroll
        for (int j = 0; j < 4; ++j) {
            int c = wn * 64 + j * 16 + lr;
            bh[j] = *reinterpret_cast<const bf16x8*>(&Bsh[c][lk]);
            bl[j] = *reinterpret_cast<const bf16x8*>(&Bsl[c][lk]);
        }
#pragma unroll
        for (int i = 0; i < 4; ++i)
#pragma unroll
            for (int j = 0; j < 4; ++j) {
                acc[i][j] = __builtin_amdgcn_mfma_f32_16x16x32_bf16(ah[i], bh[j], acc[i][j], 0, 0, 0);
                acc[i][j] = __builtin_amdgcn_mfma_f32_16x16x32_bf16(ah[i], bl[j], acc[i][j], 0, 0, 0);
                acc[i][j] = __builtin_amdgcn_mfma_f32_16x16x32_bf16(al[i], bh[j], acc[i][j], 0, 0, 0);
            }
    }

#pragma unroll
    for (int i = 0; i < 4; ++i) {
#pragma unroll
        for (int r = 0; r < 4; ++r) {
            int row_g = bm + wm * 64 + i * 16 + (l >> 4) * 4 + r;
            if (row_g >= M) continue;
#pragma unroll
            for (int j = 0; j < 4; ++j) {
                int col_g = bn + wn * 64 + j * 16 + lr;
                Cb[(size_t)row_g * Nc + col_g] = f2bf(acc[i][j][r]);
            }
        }
    }
}

// ---------------- layers-2/3 GEMM: bf16 A (2 products) ----------------

__global__ __launch_bounds__(256) void gemm_bf16a_k(const unsigned short* __restrict__ A,
                                                    const unsigned short* __restrict__ Bh,
                                                    const unsigned short* __restrict__ Bl,
                                                    unsigned short* __restrict__ Cb,
                                                    int M, int K, int Nc) {
    __shared__ unsigned short As[128][GPAD];
    __shared__ unsigned short Bsh[128][GPAD];
    __shared__ unsigned short Bsl[128][GPAD];

    int bm = blockIdx.y * 128;
    int bn = blockIdx.x * 128;
    int t = threadIdx.x;
    int w = t >> 6, l = t & 63;
    int wm = w >> 1, wn = w & 1;
    int lr = l & 15, lk = (l >> 4) * 8;

    int srow = t >> 1;
    int skh  = (t & 1) * 16;

    f32x4 acc[4][4];
#pragma unroll
    for (int i = 0; i < 4; ++i)
#pragma unroll
        for (int j = 0; j < 4; ++j)
            acc[i][j] = (f32x4){0.f, 0.f, 0.f, 0.f};

    const int arow = bm + srow;
    const bool arow_ok = (arow < M);
    const size_t acol_base = (size_t)arow * K + skh;
    const size_t bcol_base = (size_t)(bn + srow) * K + skh;

    for (int k0 = 0; k0 < K; k0 += 32) {
        __syncthreads();
        {
            uint4* da = reinterpret_cast<uint4*>(&As[srow][skh]);
            if (arow_ok) {
                const uint4* sa = reinterpret_cast<const uint4*>(A + acol_base + k0);
                da[0] = sa[0]; da[1] = sa[1];
            } else {
                da[0] = make_uint4(0u, 0u, 0u, 0u);
                da[1] = make_uint4(0u, 0u, 0u, 0u);
            }
            const uint4* sh = reinterpret_cast<const uint4*>(Bh + bcol_base + k0);
            const uint4* sl = reinterpret_cast<const uint4*>(Bl + bcol_base + k0);
            uint4* dh = reinterpret_cast<uint4*>(&Bsh[srow][skh]);
            uint4* dl = reinterpret_cast<uint4*>(&Bsl[srow][skh]);
            dh[0] = sh[0]; dh[1] = sh[1];
            dl[0] = sl[0]; dl[1] = sl[1];
        }
        __syncthreads();

        bf16x8 ah[4], bh[4], bl[4];
#pragma unroll
        for (int i = 0; i < 4; ++i) {
            int r = wm * 64 + i * 16 + lr;
            ah[i] = *reinterpret_cast<const bf16x8*>(&As[r][lk]);
        }
#pragma unroll
        for (int j = 0; j < 4; ++j) {
            int c = wn * 64 + j * 16 + lr;
            bh[j] = *reinterpret_cast<const bf16x8*>(&Bsh[c][lk]);
            bl[j] = *reinterpret_cast<const bf16x8*>(&Bsl[c][lk]);
        }
#pragma unroll
        for (int i = 0; i < 4; ++i)
#pragma unroll
            for (int j = 0; j < 4; ++j) {
                acc[i][j] = __builtin_amdgcn_mfma_f32_16x16x32_bf16(ah[i], bh[j], acc[i][j], 0, 0, 0);
                acc[i][j] = __builtin_amdgcn_mfma_f32_16x16x32_bf16(ah[i], bl[j], acc[i][j], 0, 0, 0);
            }
    }

#pragma unroll
    for (int i = 0; i < 4; ++i) {
#pragma unroll
        for (int r = 0; r < 4; ++r) {
            int row_g = bm + wm * 64 + i * 16 + (l >> 4) * 4 + r;
            if (row_g >= M) continue;
#pragma unroll
            for (int j = 0; j < 4; ++j) {
                int col_g = bn + wn * 64 + j * 16 + lr;
                Cb[(size_t)row_g * Nc + col_g] = f2bf(acc[i][j][r]);
            }
        }
    }
}

// ---------------- attention logit precompute: persistent wave per node ----------------

__global__ __launch_bounds__(256) void compute_al_k(const unsigned short* __restrict__ h,
                                                    const float* __restrict__ a_src,
                                                    const float* __restrict__ a_dst,
                                                    float* __restrict__ al_s,
                                                    float* __restrict__ al_d, int n) {
    int gw = blockIdx.x * 4 + (threadIdx.x >> 6);
    int nw = gridDim.x * 4;
    int lane = threadIdx.x & 63;
    float4 asv = reinterpret_cast<const float4*>(a_src)[lane];
    float4 adv = reinterpret_cast<const float4*>(a_dst)[lane];
    for (int node = gw; node < n; node += nw) {
        ushort4 v = reinterpret_cast<const ushort4*>(h + (size_t)node * 256)[lane];
        float ps = bf2f(v.x) * asv.x + bf2f(v.y) * asv.y + bf2f(v.z) * asv.z + bf2f(v.w) * asv.w;
        float pd = bf2f(v.x) * adv.x + bf2f(v.y) * adv.y + bf2f(v.z) * adv.z + bf2f(v.w) * adv.w;
#pragma unroll
        for (int off = 1; off < 8; off <<= 1) {
            ps += __shfl_xor(ps, off, 64);
            pd += __shfl_xor(pd, off, 64);
        }
        if ((lane & 7) == 0) {
            al_s[node * 8 + (lane >> 3)] = ps;
            al_d[node * 8 + (lane >> 3)] = pd;
        }
    }
}

__global__ void compute_al3_k(const unsigned short* __restrict__ h,
                              const float* __restrict__ a_src, const float* __restrict__ a_dst,
                              float* __restrict__ al_s, float* __restrict__ al_d, int n) {
    int wid = threadIdx.x >> 6, lane = threadIdx.x & 63;
    int node = blockIdx.x * 4 + wid;
    if (node >= n) return;
    float hv = (lane < 40) ? bf2f(h[(size_t)node * 128 + lane]) : 0.f;
    float ps = (lane < 40) ? hv * a_src[lane] : 0.f;
    float pd = (lane < 40) ? hv * a_dst[lane] : 0.f;
#pragma unroll
    for (int off = 32; off; off >>= 1) {
        ps += __shfl_xor(ps, off, 64);
        pd += __shfl_xor(pd, off, 64);
    }
    if (lane == 0) { al_s[node] = ps; al_d[node] = pd; }
}

// ---------------- edge softmax: WAVE per dst (8 edge slots x 8 heads) ----------------

__global__ __launch_bounds__(256) void edge_softmax_wave_k(const float* __restrict__ al_s,
                                                           const float* __restrict__ al_d,
                                                           const int* __restrict__ row_ptr,
                                                           const int* __restrict__ srcs,
                                                           float* __restrict__ w,
                                                           float* __restrict__ inv, int n) {
    int gw = blockIdx.x * 4 + (threadIdx.x >> 6);
    int nw = gridDim.x * 4;
    int lane = threadIdx.x & 63;
    int es = lane >> 3, hd = lane & 7;
    for (int dst = gw; dst < n; dst += nw) {
        int beg = row_ptr[dst], end = row_ptr[dst + 1];
        float ald = al_d[dst * 8 + hd];
        float m = -1e30f;
        for (int i = beg + es; i < end; i += 8) {
            int s = srcs[i];
            float l = al_s[s * 8 + hd] + ald;
            l = (l > 0.f) ? l : NEG_SLOPE * l;
            m = fmaxf(m, l);
        }
        m = fmaxf(m, __shfl_xor(m, 8, 64));
        m = fmaxf(m, __shfl_xor(m, 16, 64));
        m = fmaxf(m, __shfl_xor(m, 32, 64));
        float sw = 0.f;
        for (int i = beg + es; i < end; i += 8) {
            int s = srcs[i];
            float l = al_s[s * 8 + hd] + ald;
            l = (l > 0.f) ? l : NEG_SLOPE * l;
            float e = __expf(l - m);
            w[(size_t)i * 8 + hd] = e;
            sw += e;
        }
        sw += __shfl_xor(sw, 8, 64);
        sw += __shfl_xor(sw, 16, 64);
        sw += __shfl_xor(sw, 32, 64);
        if (es == 0) inv[dst * 8 + hd] = 1.f / (sw + 1e-16f);
    }
}

// layer 3: wave per dst, single head, 64 edge slots
__global__ __launch_bounds__(256) void edge_softmax3_wave_k(const float* __restrict__ al_s,
                                                            const float* __restrict__ al_d,
                                                            const int* __restrict__ row_ptr,
                                                            const int* __restrict__ srcs,
                                                            float* __restrict__ w,
                                                            float* __restrict__ inv, int n) {
    int gw = blockIdx.x * 4 + (threadIdx.x >> 6);
    int nw = gridDim.x * 4;
    int lane = threadIdx.x & 63;
    for (int dst = gw; dst < n; dst += nw) {
        int beg = row_ptr[dst], end = row_ptr[dst + 1];
        float ald = al_d[dst];
        float m = -1e30f;
        for (int i = beg + lane; i < end; i += 64) {
            int s = srcs[i];
            float l = al_s[s] + ald;
            l = (l > 0.f) ? l : NEG_SLOPE * l;
            m = fmaxf(m, l);
        }
#pragma unroll
        for (int off = 32; off; off >>= 1) m = fmaxf(m, __shfl_xor(m, off, 64));
        float sw = 0.f;
        for (int i = beg + lane; i < end; i += 64) {
            int s = srcs[i];
            float l = al_s[s] + ald;
            l = (l > 0.f) ? l : NEG_SLOPE * l;
            float e = __expf(l - m);
            w[i] = e;
            sw += e;
        }
#pragma unroll
        for (int off = 32; off; off >>= 1) sw += __shfl_xor(sw, off, 64);
        if (lane == 0) inv[dst] = 1.f / (sw + 1e-16f);
    }
}

// ---------------- gather-FMA aggregation: wave per PAIR of dsts, 2 chains, batch-4 ----------------

template <bool ELU>
__global__ __launch_bounds__(256) void gat_gather_pair_k(const unsigned short* __restrict__ h,
                                                         const float* __restrict__ w,
                                                         const float* __restrict__ inv,
                                                         const int* __restrict__ row_ptr,
                                                         const int* __restrict__ srcs,
                                                         const float* __restrict__ bias,
                                                         unsigned short* __restrict__ out, int npairs) {
    int gw = blockIdx.x * 4 + (threadIdx.x >> 6);
    int nw = gridDim.x * 4;
    int lane = threadIdx.x & 63;
    int hd = lane >> 3;
    const ushort4* hp = reinterpret_cast<const ushort4*>(h);
    float4 b4 = reinterpret_cast<const float4*>(bias)[lane];

    for (int p = gw; p < npairs; p += nw) {
        int dstA = 2 * p, dstB = 2 * p + 1;
        int begA = row_ptr[dstA], endA = row_ptr[dstA + 1], endB = row_ptr[dstB + 1];
        int begB = endA;
        float4 accA = make_float4(0.f, 0.f, 0.f, 0.f);
        float4 accB = make_float4(0.f, 0.f, 0.f, 0.f);
        int iA = begA, iB = begB;
        int nbA = (endA - begA + 3) >> 2;
        int nbB = (endB - begB + 3) >> 2;
        int nb = (nbA > nbB) ? nbA : nbB;
        for (int b = 0; b < nb; ++b) {
            int sA[4], sB[4];
            float wA[4], wB[4];
#pragma unroll
            for (int k = 0; k < 4; ++k) {
                int ia = iA + k;
                int idxA = (ia < endA) ? ia : (endA - 1);
                sA[k] = srcs[idxA];
                float wa = w[(size_t)idxA * 8 + hd];
                wA[k] = (ia < endA) ? wa : 0.f;
                int ib = iB + k;
                int idxB = (ib < endB) ? ib : (endB - 1);
                sB[k] = srcs[idxB];
                float wb = w[(size_t)idxB * 8 + hd];
                wB[k] = (ib < endB) ? wb : 0.f;
            }
            ushort4 vA[4], vB[4];
#pragma unroll
            for (int k = 0; k < 4; ++k) vA[k] = hp[(size_t)sA[k] * 64 + lane];
#pragma unroll
            for (int k = 0; k < 4; ++k) vB[k] = hp[(size_t)sB[k] * 64 + lane];
#pragma unroll
            for (int k = 0; k < 4; ++k) {
                accA.x = fmaf(wA[k], bf2f(vA[k].x), accA.x);
                accA.y = fmaf(wA[k], bf2f(vA[k].y), accA.y);
                accA.z = fmaf(wA[k], bf2f(vA[k].z), accA.z);
                accA.w = fmaf(wA[k], bf2f(vA[k].w), accA.w);
                accB.x = fmaf(wB[k], bf2f(vB[k].x), accB.x);
                accB.y = fmaf(wB[k], bf2f(vB[k].y), accB.y);
                accB.z = fmaf(wB[k], bf2f(vB[k].z), accB.z);
                accB.w = fmaf(wB[k], bf2f(vB[k].w), accB.w);
            }
            iA += 4; iB += 4;
        }

        float ivA = inv[dstA * 8 + hd];
        float ivB = inv[dstB * 8 + hd];
        float4 oA, oB;
        oA.x = accA.x * ivA + b4.x; oA.y = accA.y * ivA + b4.y;
        oA.z = accA.z * ivA + b4.z; oA.w = accA.w * ivA + b4.w;
        oB.x = accB.x * ivB + b4.x; oB.y = accB.y * ivB + b4.y;
        oB.z = accB.z * ivB + b4.z; oB.w = accB.w * ivB + b4.w;
        if (ELU) {
            oA.x = (oA.x > 0.f) ? oA.x : expm1f(oA.x);
            oA.y = (oA.y > 0.f) ? oA.y : expm1f(oA.y);
            oA.z = (oA.z > 0.f) ? oA.z : expm1f(oA.z);
            oA.w = (oA.w > 0.f) ? oA.w : expm1f(oA.w);
            oB.x = (oB.x > 0.f) ? oB.x : expm1f(oB.x);
            oB.y = (oB.y > 0.f) ? oB.y : expm1f(oB.y);
            oB.z = (oB.z > 0.f) ? oB.z : expm1f(oB.z);
            oB.w = (oB.w > 0.f) ? oB.w : expm1f(oB.w);
        }
        ushort4 obA, obB;
        obA.x = f2bf(oA.x); obA.y = f2bf(oA.y); obA.z = f2bf(oA.z); obA.w = f2bf(oA.w);
        obB.x = f2bf(oB.x); obB.y = f2bf(oB.y); obB.z = f2bf(oB.z); obB.w = f2bf(oB.w);
        reinterpret_cast<ushort4*>(out + (size_t)dstA * 256)[lane] = obA;
        reinterpret_cast<ushort4*>(out + (size_t)dstB * 256)[lane] = obB;
    }
}

// layer 3: persistent wave per dst, 4 edges in parallel (16 lanes x ushort4 each); fp32 out
__global__ __launch_bounds__(256) void gat_gather3_k(const unsigned short* __restrict__ h,
                                                     const float* __restrict__ w,
                                                     const float* __restrict__ inv,
                                                     const int* __restrict__ row_ptr,
                                                     const int* __restrict__ srcs,
                                                     const float* __restrict__ bias,
                                                     float* __restrict__ out, int n) {
    int gw = blockIdx.x * 4 + (threadIdx.x >> 6);
    int nw = gridDim.x * 4;
    int lane = threadIdx.x & 63;
    int es = lane >> 4, cl = lane & 15;

    for (int dst = gw; dst < n; dst += nw) {
        int beg = row_ptr[dst], end = row_ptr[dst + 1];
        float4 acc = make_float4(0.f, 0.f, 0.f, 0.f);
        for (int i = beg; i < end; i += 4) {
            int idx = i + es;
            bool ok = (idx < end);
            int s = ok ? srcs[idx] : srcs[beg];
            float wgt = ok ? w[idx] : 0.f;
            ushort4 v = reinterpret_cast<const ushort4*>(h + (size_t)s * 128)[cl];
            acc.x = fmaf(wgt, bf2f(v.x), acc.x);
            acc.y = fmaf(wgt, bf2f(v.y), acc.y);
            acc.z = fmaf(wgt, bf2f(v.z), acc.z);
            acc.w = fmaf(wgt, bf2f(v.w), acc.w);
        }
#pragma unroll
        for (int off = 16; off <= 32; off <<= 1) {
            acc.x += __shfl_xor(acc.x, off, 64);
            acc.y += __shfl_xor(acc.y, off, 64);
            acc.z += __shfl_xor(acc.z, off, 64);
            acc.w += __shfl_xor(acc.w, off, 64);
        }
        if (es == 0 && cl < 10) {
            float iv = inv[dst];
            int c = cl * 4;
            float4 b4 = *reinterpret_cast<const float4*>(bias + c);
            float4 o;
            o.x = acc.x * iv + b4.x;
            o.y = acc.y * iv + b4.y;
            o.z = acc.z * iv + b4.z;
            o.w = acc.w * iv + b4.w;
            *reinterpret_cast<float4*>(out + (size_t)dst * 40 + c) = o;
        }
    }
}

// ---------------- launch ----------------

extern "C" void kernel_launch(void* const* d_in, const int* in_sizes, int n_in,
                              void* d_out, int out_size, void* d_ws, size_t ws_size,
                              hipStream_t stream) {
    const float* x   = (const float*)d_in[0];
    const int*   ei  = (const int*)d_in[1];
    const float* W1  = (const float*)d_in[2];
    const float* as1 = (const float*)d_in[3];
    const float* ad1 = (const float*)d_in[4];
    const float* b1  = (const float*)d_in[5];
    const float* W2  = (const float*)d_in[6];
    const float* as2 = (const float*)d_in[7];
    const float* ad2 = (const float*)d_in[8];
    const float* b2  = (const float*)d_in[9];
    const float* W3  = (const float*)d_in[10];
    const float* as3 = (const float*)d_in[11];
    const float* ad3 = (const float*)d_in[12];
    const float* b3  = (const float*)d_in[13];

    const int N = in_sizes[0] / 128;   // 50000
    const int E = in_sizes[1] / 2;     // 800000
    const int ET = E + N;

    char* ws = (char*)d_ws;
    size_t off = 0;
    auto alloc = [&](size_t bytes) -> void* {
        void* p = ws + off;
        off += (bytes + 255) & ~(size_t)255;
        return p;
    };
    int*   row_ptr = (int*)alloc(sizeof(int) * (N + 1));
    int*   pos     = (int*)alloc(sizeof(int) * N);
    int*   srcs    = (int*)alloc(sizeof(int) * ET);
    int*   bsums   = (int*)alloc(sizeof(int) * 64);
    float* als     = (float*)alloc(sizeof(float) * N * 8);
    float* ald     = (float*)alloc(sizeof(float) * N * 8);
    float* wbuf    = (float*)alloc(sizeof(float) * (size_t)ET * 8);
    float* invb    = (float*)alloc(sizeof(float) * N * 8);
    unsigned short* hb16 = (unsigned short*)alloc(sizeof(unsigned short) * (size_t)N * 256);
    unsigned short* ab16 = (unsigned short*)alloc(sizeof(unsigned short) * (size_t)N * 256);
    unsigned short* wb1h = (unsigned short*)alloc(sizeof(unsigned short) * 128 * 256);
    unsigned short* wb1l = (unsigned short*)alloc(sizeof(unsigned short) * 128 * 256);
    unsigned short* wb2h = (unsigned short*)alloc(sizeof(unsigned short) * 256 * 256);
    unsigned short* wb2l = (unsigned short*)alloc(sizeof(unsigned short) * 256 * 256);
    unsigned short* wb3h = (unsigned short*)alloc(sizeof(unsigned short) * 128 * 256);
    unsigned short* wb3l = (unsigned short*)alloc(sizeof(unsigned short) * 128 * 256);
    (void)ws_size;

    const int nb = (N + 1023) / 1024;
    const int PG = 2048;

    convert_w_all_k<<<(R1 + R2 + R3 + 255) / 256, 256, 0, stream>>>(
        W1, W2, W3, wb1h, wb1l, wb2h, wb2l, wb3h, wb3l);

    hipMemsetAsync(pos, 0, sizeof(int) * N, stream);
    count_edges_k<<<(ET + 255) / 256, 256, 0, stream>>>(ei, E, N, pos);
    scan1_k<<<nb, 256, 0, stream>>>(pos, row_ptr, bsums, N);
    scan2_k<<<1, 64, 0, stream>>>(bsums, nb);
    scan3_k<<<(N + 1 + 255) / 256, 256, 0, stream>>>(row_ptr, pos, bsums, N, ET);
    scatter_edges_k<<<(ET + 255) / 256, 256, 0, stream>>>(ei, E, N, pos, srcs);

    const int gy = (N + 127) / 128;
    const int gagg = (N + 3) / 4;
    const int npairs = N / 2;

    // --- layer 1 ---
    mfma_gemm_k<<<dim3(2, gy), 256, 0, stream>>>(x, wb1h, wb1l, hb16, N, 128, 256);
    compute_al_k<<<PG, 256, 0, stream>>>(hb16, as1, ad1, als, ald, N);
    edge_softmax_wave_k<<<PG, 256, 0, stream>>>(als, ald, row_ptr, srcs, wbuf, invb, N);
    gat_gather_pair_k<true><<<PG, 256, 0, stream>>>(hb16, wbuf, invb, row_ptr, srcs, b1, ab16, npairs);

    // --- layer 2 ---
    gemm_bf16a_k<<<dim3(2, gy), 256, 0, stream>>>(ab16, wb2h, wb2l, hb16, N, 256, 256);
    compute_al_k<<<PG, 256, 0, stream>>>(hb16, as2, ad2, als, ald, N);
    edge_softmax_wave_k<<<PG, 256, 0, stream>>>(als, ald, row_ptr, srcs, wbuf, invb, N);
    gat_gather_pair_k<true><<<PG, 256, 0, stream>>>(hb16, wbuf, invb, row_ptr, srcs, b2, ab16, npairs);

    // --- layer 3 ---
    gemm_bf16a_k<<<dim3(1, gy), 256, 0, stream>>>(ab16, wb3h, wb3l, hb16, N, 256, 128);
    compute_al3_k<<<gagg, 256, 0, stream>>>(hb16, as3, ad3, als, ald, N);
    edge_softmax3_wave_k<<<PG, 256, 0, stream>>>(als, ald, row_ptr, srcs, wbuf, invb, N);
    gat_gather3_k<<<PG, 256, 0, stream>>>(hb16, wbuf, invb, row_ptr, srcs, b3, (float*)d_out, N);
}